// Round 12
// baseline (456.247 us; speedup 1.0000x reference)
//
#include <hip/hip_runtime.h>
#include <math.h>

#define D 128
#define K 256
#define DQ (D/4)

typedef __attribute__((ext_vector_type(8))) short short8;
typedef __attribute__((ext_vector_type(4))) float float4v;

// ---- ws layout (float offsets). Total ~528 KB. ----
#define WS_INTER  0                 // 1 float
#define WS_C2     16                // K floats
#define WS_COUNTS (16 + K)          // K floats
#define WS_DEVSUM (16 + 2*K)        // K floats
#define WS_MEANS  1024              // K*D floats (sums, then means in place)
#define WS_CHI    33792             // K*D bf16 hi
#define WS_CLO    50176             // K*D bf16 lo
#define WS_ASSIGN 66560             // N uchar

__device__ inline ushort bf16_rne(float f) {
  union { float f; uint u; } c; c.f = f;
  return (ushort)((c.u + 0x7FFFu + ((c.u >> 16) & 1u)) >> 16);
}
__device__ inline float bf16_to_f(ushort h) {
  union { uint u; float f; } c; c.u = ((uint)h) << 16; return c.f;
}

// ---- center prep: bf16 hi/lo split, |c|^2, zero all accumulators --------
__global__ __launch_bounds__(128) void k_cprep(const float* __restrict__ centers,
                                               float* __restrict__ ws) {
  const int k = blockIdx.x, d = threadIdx.x;
  const float v = centers[(size_t)k * D + d];
  const ushort hi = bf16_rne(v);
  const float lo = v - bf16_to_f(hi);
  ((ushort*)(ws + WS_CHI))[k * D + d] = hi;
  ((ushort*)(ws + WS_CLO))[k * D + d] = bf16_rne(lo);
  ws[WS_MEANS + k * D + d] = 0.0f;          // zero sums (atomics target)
  __shared__ float red[D];
  red[d] = v * v;
  __syncthreads();
  for (int s = 64; s > 0; s >>= 1) {
    if (d < s) red[d] += red[d + s];
    __syncthreads();
  }
  if (d == 0) {
    ws[WS_C2 + k] = red[0];
    ws[WS_DEVSUM + k] = 0.0f;
    ws[WS_COUNTS + k] = 0.0f;
    if (k == 0) ws[WS_INTER] = 0.0f;
  }
}

// ---- inter-cluster: count upper-tri pairs with dist < 1 (sq < 1) --------
__global__ __launch_bounds__(256) void k_inter(const float* __restrict__ centers,
                                               float* __restrict__ ws) {
  const int i = blockIdx.x;
  const int j = threadIdx.x;
  __shared__ __align__(16) float ci[D];
  __shared__ int cnt;
  if (j == 0) cnt = 0;
  if (j < D) ci[j] = centers[(size_t)i * D + j];
  __syncthreads();
  int hit = 0;
  if (j > i) {
    const float4* cj = (const float4*)(centers + (size_t)j * D);
    const float4* cis = (const float4*)ci;
    float dot = 0.0f;
#pragma unroll
    for (int q = 0; q < DQ; ++q) {
      float4 a = cis[q];
      float4 b = cj[q];
      dot = fmaf(a.x, b.x, fmaf(a.y, b.y, fmaf(a.z, b.z, fmaf(a.w, b.w, dot))));
    }
    const float sq = ws[WS_C2 + i] + ws[WS_C2 + j] - 2.0f * dot;
    hit = (sq < 1.0f) ? 1 : 0;
  }
  if (hit) atomicAdd(&cnt, 1);
  __syncthreads();
  if (j == 0 && cnt > 0) atomicAdd(&ws[WS_INTER], (float)cnt);
}

// ---- assignment via bf16 hi/lo MFMA: argmin_k (|c_k|^2 - 2 f.c_k) -------
// 2 point-tiles per wave (32 points): live set ~105-120 regs incl. acc ->
// lands in the <=128 occupancy bin = 4 waves/SIMD for latency hiding.
// NO min-waves bound (measured r10: it halves the arch budget -> spill).
// A and B packed with the SAME lane->(index, k-group) map, so the HW's
// internal within-lane k ordering cancels. D layout: col=lane&15 (center),
// row=(lane>>4)*4+reg (point) [HW-verified].
__global__ __launch_bounds__(256) void k_assign(
    const float* __restrict__ feat,
    const ushort* __restrict__ chi,
    const ushort* __restrict__ clo,
    const float* __restrict__ c2,
    unsigned char* __restrict__ assign) {
  const int tid = threadIdx.x;
  const int wave = tid >> 6, lane = tid & 63;
  const int lr = lane & 15;
  const int g = lane >> 4;
  const int rowbase = blockIdx.x * 128 + wave * 32;

  short8 ahi[2][4], alo[2][4];
#pragma unroll
  for (int t = 0; t < 2; ++t) {
    const float* fr = feat + (size_t)(rowbase + t * 16 + lr) * D + g * 8;
#pragma unroll
    for (int s = 0; s < 4; ++s) {
      const float4 p0 = *(const float4*)(fr + s * 32);
      const float4 p1 = *(const float4*)(fr + s * 32 + 4);
      const float fv[8] = {p0.x, p0.y, p0.z, p0.w, p1.x, p1.y, p1.z, p1.w};
#pragma unroll
      for (int j = 0; j < 8; ++j) {
        const ushort h = bf16_rne(fv[j]);
        ahi[t][s][j] = (short)h;
        alo[t][s][j] = (short)bf16_rne(fv[j] - bf16_to_f(h));
      }
    }
  }

  float bestv[2][4];
  int bidx[2][4];
#pragma unroll
  for (int t = 0; t < 2; ++t)
#pragma unroll
    for (int r = 0; r < 4; ++r) { bestv[t][r] = 3.402823466e38f; bidx[t][r] = 0; }

  for (int bt = 0; bt < 16; ++bt) {
    const int cidx = bt * 16 + lr;
    const float c2v = c2[cidx];
    float4v acc[2];
#pragma unroll
    for (int t = 0; t < 2; ++t) acc[t] = (float4v){0.f, 0.f, 0.f, 0.f};
#pragma unroll
    for (int s = 0; s < 4; ++s) {
      const size_t boff = (size_t)cidx * D + s * 32 + g * 8;
      const short8 bh = *(const short8*)(chi + boff);
      const short8 bl = *(const short8*)(clo + boff);
#pragma unroll
      for (int t = 0; t < 2; ++t) {
        acc[t] = __builtin_amdgcn_mfma_f32_16x16x32_bf16(ahi[t][s], bh, acc[t], 0, 0, 0);
        acc[t] = __builtin_amdgcn_mfma_f32_16x16x32_bf16(alo[t][s], bh, acc[t], 0, 0, 0);
        acc[t] = __builtin_amdgcn_mfma_f32_16x16x32_bf16(ahi[t][s], bl, acc[t], 0, 0, 0);
      }
    }
#pragma unroll
    for (int t = 0; t < 2; ++t)
#pragma unroll
      for (int r = 0; r < 4; ++r) {
        const float sc = fmaf(-2.0f, acc[t][r], c2v);
        if (sc < bestv[t][r]) { bestv[t][r] = sc; bidx[t][r] = cidx; }
      }
  }

#pragma unroll
  for (int t = 0; t < 2; ++t)
#pragma unroll
    for (int r = 0; r < 4; ++r) {
      float v = bestv[t][r];
      int i = bidx[t][r];
#pragma unroll
      for (int m = 1; m < 16; m <<= 1) {
        const float ov = __shfl_xor(v, m);
        const int oi = __shfl_xor(i, m);
        if (ov < v || (ov == v && oi < i)) { v = ov; i = oi; }
      }
      if (lr == 0) assign[rowbase + t * 16 + g * 4 + r] = (unsigned char)i;
    }
}

// ---- means partials: 8 slices per cluster, grid K*8, atomic combine -----
// 8 blocks/CU (32 waves/CU); gather 8 rows in flight per wave for MLP.
#define SEG 4096
#define SLICES 8
__global__ __launch_bounds__(256) void k_means_part(const float* __restrict__ feat,
                                                    const unsigned char* __restrict__ assign,
                                                    float* __restrict__ sums,
                                                    float* __restrict__ counts, int N) {
  const int k = blockIdx.x >> 3;
  const int slice = blockIdx.x & (SLICES - 1);
  const int tid = threadIdx.x;
  const int wave = tid >> 6, lane = tid & 63;
  __shared__ float accsh[4][D];
  __shared__ int queue[SEG];
  __shared__ int qn, total;
  float ax = 0.0f, ay = 0.0f;   // lane's partial for dims 2*lane, 2*lane+1
  if (tid == 0) total = 0;
  const int sbeg = slice * (N / SLICES);
  const int send = sbeg + N / SLICES;
  for (int base = sbeg; base < send; base += SEG) {
    if (tid == 0) qn = 0;
    __syncthreads();
    const uint4 w = *(const uint4*)(assign + base + tid * 16);
    const uint words[4] = {w.x, w.y, w.z, w.w};
#pragma unroll
    for (int wq = 0; wq < 4; ++wq)
#pragma unroll
      for (int b = 0; b < 4; ++b) {
        if (((words[wq] >> (8 * b)) & 0xFFu) == (uint)k) {
          const int pos = atomicAdd(&qn, 1);
          queue[pos] = base + tid * 16 + wq * 4 + b;
        }
      }
    __syncthreads();
    const int n = qn;
    if (tid == 0) total += n;
    int r = wave;
    // 8 rows in flight per wave
    for (; r + 28 < n; r += 32) {
      int idx[8];
#pragma unroll
      for (int q = 0; q < 8; ++q) idx[q] = queue[r + 4 * q];
      float2 v[8];
#pragma unroll
      for (int q = 0; q < 8; ++q) v[q] = *(const float2*)(feat + (size_t)idx[q] * D + 2 * lane);
#pragma unroll
      for (int q = 0; q < 8; ++q) { ax += v[q].x; ay += v[q].y; }
    }
    // 4 rows in flight
    for (; r + 12 < n; r += 16) {
      const int i0 = queue[r], i1 = queue[r + 4], i2 = queue[r + 8], i3 = queue[r + 12];
      const float2 v0 = *(const float2*)(feat + (size_t)i0 * D + 2 * lane);
      const float2 v1 = *(const float2*)(feat + (size_t)i1 * D + 2 * lane);
      const float2 v2 = *(const float2*)(feat + (size_t)i2 * D + 2 * lane);
      const float2 v3 = *(const float2*)(feat + (size_t)i3 * D + 2 * lane);
      ax += (v0.x + v1.x) + (v2.x + v3.x);
      ay += (v0.y + v1.y) + (v2.y + v3.y);
    }
    for (; r < n; r += 4) {
      const float2 v = *(const float2*)(feat + (size_t)queue[r] * D + 2 * lane);
      ax += v.x;
      ay += v.y;
    }
    __syncthreads();
  }
  accsh[wave][2 * lane] = ax;
  accsh[wave][2 * lane + 1] = ay;
  __syncthreads();
  if (tid < D) {
    const float s = (accsh[0][tid] + accsh[1][tid]) + (accsh[2][tid] + accsh[3][tid]);
    atomicAdd(&sums[k * D + tid], s);
  }
  if (tid == 0 && total > 0) atomicAdd(&counts[k], (float)total);
}

// ---- finalize means: sums/count in place --------------------------------
__global__ __launch_bounds__(128) void k_meansfin(float* __restrict__ sums,
                                                  const float* __restrict__ counts) {
  const int k = blockIdx.x, d = threadIdx.x;
  sums[k * D + d] /= fmaxf(counts[k], 1.0f);
}

// ---- deviations: wave-per-row coalesced, shfl reduce, 4 rows/iter -------
// stride 16, rows {r, r+4, r+8, r+12}: residues (mod 16) = {w,w+4,w+8,w+12}
// for w=0..3 cover 0..15 exactly once.
__global__ __launch_bounds__(256) void k_dev(const float* __restrict__ feat,
                                             const unsigned char* __restrict__ assign,
                                             const float* __restrict__ means,
                                             float* __restrict__ devsum) {
  __shared__ float dacc[K];
  const int tid = threadIdx.x;
  const int wave = tid >> 6, lane = tid & 63;
  dacc[tid] = 0.0f;
  __syncthreads();
  const int rowbase = blockIdx.x * 256;
  for (int r = wave; r < 256; r += 16) {   // 4 rows (8 loads) in flight
    const int r0 = rowbase + r, r1 = rowbase + r + 4;
    const int r2 = rowbase + r + 8, r3 = rowbase + r + 12;
    const int a0 = (int)assign[r0];
    const int a1 = (int)assign[r1];
    const int a2 = (int)assign[r2];
    const int a3 = (int)assign[r3];
    const float2 f0 = *(const float2*)(feat + (size_t)r0 * D + 2 * lane);
    const float2 m0 = *(const float2*)(means + (size_t)a0 * D + 2 * lane);
    const float2 f1 = *(const float2*)(feat + (size_t)r1 * D + 2 * lane);
    const float2 m1 = *(const float2*)(means + (size_t)a1 * D + 2 * lane);
    const float2 f2 = *(const float2*)(feat + (size_t)r2 * D + 2 * lane);
    const float2 m2 = *(const float2*)(means + (size_t)a2 * D + 2 * lane);
    const float2 f3 = *(const float2*)(feat + (size_t)r3 * D + 2 * lane);
    const float2 m3 = *(const float2*)(means + (size_t)a3 * D + 2 * lane);
    const float dx0 = f0.x - m0.x, dy0 = f0.y - m0.y;
    const float dx1 = f1.x - m1.x, dy1 = f1.y - m1.y;
    const float dx2 = f2.x - m2.x, dy2 = f2.y - m2.y;
    const float dx3 = f3.x - m3.x, dy3 = f3.y - m3.y;
    float s0 = fmaf(dx0, dx0, dy0 * dy0);
    float s1 = fmaf(dx1, dx1, dy1 * dy1);
    float s2 = fmaf(dx2, dx2, dy2 * dy2);
    float s3 = fmaf(dx3, dx3, dy3 * dy3);
#pragma unroll
    for (int m = 1; m < 64; m <<= 1) {
      s0 += __shfl_xor(s0, m);
      s1 += __shfl_xor(s1, m);
      s2 += __shfl_xor(s2, m);
      s3 += __shfl_xor(s3, m);
    }
    if (lane == 0) {
      atomicAdd(&dacc[a0], sqrtf(s0));
      atomicAdd(&dacc[a1], sqrtf(s1));
      atomicAdd(&dacc[a2], sqrtf(s2));
      atomicAdd(&dacc[a3], sqrtf(s3));
    }
  }
  __syncthreads();
  atomicAdd(&devsum[tid], dacc[tid]);
}

// ---- final scalar combine -----------------------------------------------
__global__ __launch_bounds__(256) void k_final(const float* __restrict__ ws,
                                               float* __restrict__ out) {
  __shared__ float s_pc[K];
  __shared__ float s_v[K];
  const int t = threadIdx.x;
  const float c = ws[WS_COUNTS + t];
  const float pc = ws[WS_DEVSUM + t] / fmaxf(c, 1.0f);
  const float valid = (c > 1.0f) ? 1.0f : 0.0f;
  s_pc[t] = valid * pc;
  s_v[t] = valid;
  __syncthreads();
  for (int s = 128; s > 0; s >>= 1) {
    if (t < s) { s_pc[t] += s_pc[t + s]; s_v[t] += s_v[t + s]; }
    __syncthreads();
  }
  if (t == 0) {
    const float nv = s_v[0];
    const float intra = (nv > 0.0f) ? (s_pc[0] / fmaxf(nv, 1.0f)) : 0.0f;
    // triu(.,1) zeroed K + K(K-1)/2 = 32896 entries; zeros < margin => counted
    const float inter = (ws[WS_INTER] + 32896.0f) / 32640.0f;
    out[0] = intra + inter;
  }
}

extern "C" void kernel_launch(void* const* d_in, const int* in_sizes, int n_in,
                              void* d_out, int out_size, void* d_ws, size_t ws_size,
                              hipStream_t stream) {
  const float* feat = (const float*)d_in[0];
  const float* centers = (const float*)d_in[1];
  float* out = (float*)d_out;
  float* ws = (float*)d_ws;
  const int N = in_sizes[0] / D;
  const ushort* chi = (const ushort*)(ws + WS_CHI);
  const ushort* clo = (const ushort*)(ws + WS_CLO);
  unsigned char* assign = (unsigned char*)(ws + WS_ASSIGN);

  k_cprep<<<K, D, 0, stream>>>(centers, ws);
  k_inter<<<K, 256, 0, stream>>>(centers, ws);
  k_assign<<<N / 128, 256, 0, stream>>>(feat, chi, clo, ws + WS_C2, assign);
  k_means_part<<<K * SLICES, 256, 0, stream>>>(feat, assign, ws + WS_MEANS, ws + WS_COUNTS, N);
  k_meansfin<<<K, D, 0, stream>>>(ws + WS_MEANS, ws + WS_COUNTS);
  k_dev<<<N / 256, 256, 0, stream>>>(feat, assign, ws + WS_MEANS, ws + WS_DEVSUM);
  k_final<<<1, 256, 0, stream>>>(ws, out);
}

// Round 14
// 341.424 us; speedup vs baseline: 1.3363x; 1.3363x over previous
//
#include <hip/hip_runtime.h>
#include <math.h>

#define D 128
#define K 256
#define DQ (D/4)

typedef __attribute__((ext_vector_type(8))) short short8;
typedef __attribute__((ext_vector_type(4))) float float4v;

// ---- ws layout (float offsets). Total ~528 KB. ----
#define WS_INTER  0                 // 1 float
#define WS_C2     16                // K floats
#define WS_COUNTS (16 + K)          // K floats
#define WS_DEVSUM (16 + 2*K)        // K floats
#define WS_MEANS  1024              // K*D floats (sums, then means in place)
#define WS_CHI    33792             // K*D bf16 hi
#define WS_CLO    50176             // K*D bf16 lo
#define WS_ASSIGN 66560             // N uchar

__device__ inline ushort bf16_rne(float f) {
  union { float f; uint u; } c; c.f = f;
  return (ushort)((c.u + 0x7FFFu + ((c.u >> 16) & 1u)) >> 16);
}
__device__ inline float bf16_to_f(ushort h) {
  union { uint u; float f; } c; c.u = ((uint)h) << 16; return c.f;
}

// ---- center prep: bf16 hi/lo split, |c|^2, zero all accumulators --------
__global__ __launch_bounds__(128) void k_cprep(const float* __restrict__ centers,
                                               float* __restrict__ ws) {
  const int k = blockIdx.x, d = threadIdx.x;
  const float v = centers[(size_t)k * D + d];
  const ushort hi = bf16_rne(v);
  const float lo = v - bf16_to_f(hi);
  ((ushort*)(ws + WS_CHI))[k * D + d] = hi;
  ((ushort*)(ws + WS_CLO))[k * D + d] = bf16_rne(lo);
  ws[WS_MEANS + k * D + d] = 0.0f;          // zero sums (atomics target)
  __shared__ float red[D];
  red[d] = v * v;
  __syncthreads();
  for (int s = 64; s > 0; s >>= 1) {
    if (d < s) red[d] += red[d + s];
    __syncthreads();
  }
  if (d == 0) {
    ws[WS_C2 + k] = red[0];
    ws[WS_DEVSUM + k] = 0.0f;
    ws[WS_COUNTS + k] = 0.0f;
    if (k == 0) ws[WS_INTER] = 0.0f;
  }
}

// ---- inter-cluster: count upper-tri pairs with dist < 1 (sq < 1) --------
__global__ __launch_bounds__(256) void k_inter(const float* __restrict__ centers,
                                               float* __restrict__ ws) {
  const int i = blockIdx.x;
  const int j = threadIdx.x;
  __shared__ __align__(16) float ci[D];
  __shared__ int cnt;
  if (j == 0) cnt = 0;
  if (j < D) ci[j] = centers[(size_t)i * D + j];
  __syncthreads();
  int hit = 0;
  if (j > i) {
    const float4* cj = (const float4*)(centers + (size_t)j * D);
    const float4* cis = (const float4*)ci;
    float dot = 0.0f;
#pragma unroll
    for (int q = 0; q < DQ; ++q) {
      float4 a = cis[q];
      float4 b = cj[q];
      dot = fmaf(a.x, b.x, fmaf(a.y, b.y, fmaf(a.z, b.z, fmaf(a.w, b.w, dot))));
    }
    const float sq = ws[WS_C2 + i] + ws[WS_C2 + j] - 2.0f * dot;
    hit = (sq < 1.0f) ? 1 : 0;
  }
  if (hit) atomicAdd(&cnt, 1);
  __syncthreads();
  if (j == 0 && cnt > 0) atomicAdd(&ws[WS_INTER], (float)cnt);
}

// ---- assignment via bf16 hi/lo MFMA: argmin_k (|c_k|^2 - 2 f.c_k) -------
// LDS-staged, double-buffered B tiles (global_load_lds, shared by 4 waves):
// per bt, B tile = 16 centers x 128 dims x (hi+lo) = 8 KB; 16 KB LDS dbuf.
// Swizzle: LDS 16B-slot (row, c) holds B[row][ (c ^ (row&7)) * 8 elems ],
// achieved by pre-swizzling the per-lane GLOBAL source (dest must stay
// linear: gload_lds writes wave-uniform base + lane*16). Reads use the
// same XOR -> ds_read_b128 conflicts capped at ~2-way (free).
// A and B packed with the SAME lane->(index, k-group) map -> HW k-order
// cancels. D layout: col=lane&15 (center), row=(lane>>4)*4+reg [verified].
__global__ __launch_bounds__(256) void k_assign(
    const float* __restrict__ feat,
    const ushort* __restrict__ chi,
    const ushort* __restrict__ clo,
    const float* __restrict__ c2,
    unsigned char* __restrict__ assign) {
  const int tid = threadIdx.x;
  const int wave = tid >> 6, lane = tid & 63;
  const int lr = lane & 15;
  const int g = lane >> 4;
  const int rowbase = blockIdx.x * 128 + wave * 32;

  // [buf][half(hi,lo)][row 0..15][128 ushorts = 256 B]
  __shared__ __align__(16) ushort ldsb[2][2][16][128];

#define STAGE_B(BUF, BT) do {                                                  \
    const int srow_ = (wave << 2) + (lane >> 4);                               \
    const int sc_ = lane & 15;                                                 \
    const int gcol_ = (sc_ ^ (srow_ & 7)) << 3;                                \
    const size_t goff_ = (size_t)(((BT) << 4) + srow_) * D + gcol_;            \
    __builtin_amdgcn_global_load_lds(                                          \
        (const __attribute__((address_space(1))) unsigned int*)(chi + goff_),  \
        (__attribute__((address_space(3))) unsigned int*)&ldsb[BUF][0][wave << 2][0], \
        16, 0, 0);                                                             \
    __builtin_amdgcn_global_load_lds(                                          \
        (const __attribute__((address_space(1))) unsigned int*)(clo + goff_),  \
        (__attribute__((address_space(3))) unsigned int*)&ldsb[BUF][1][wave << 2][0], \
        16, 0, 0);                                                             \
  } while (0)

  // ---- load + split features: 2 tiles x 4 k-steps, 8 elems/lane ----
  short8 ahi[2][4], alo[2][4];
#pragma unroll
  for (int t = 0; t < 2; ++t) {
    const float* fr = feat + (size_t)(rowbase + t * 16 + lr) * D + g * 8;
#pragma unroll
    for (int s = 0; s < 4; ++s) {
      const float4 p0 = *(const float4*)(fr + s * 32);
      const float4 p1 = *(const float4*)(fr + s * 32 + 4);
      const float fv[8] = {p0.x, p0.y, p0.z, p0.w, p1.x, p1.y, p1.z, p1.w};
#pragma unroll
      for (int j = 0; j < 8; ++j) {
        const ushort h = bf16_rne(fv[j]);
        ahi[t][s][j] = (short)h;
        alo[t][s][j] = (short)bf16_rne(fv[j] - bf16_to_f(h));
      }
    }
  }

  float bestv[2][4];
  int bidx[2][4];
#pragma unroll
  for (int t = 0; t < 2; ++t)
#pragma unroll
    for (int r = 0; r < 4; ++r) { bestv[t][r] = 3.402823466e38f; bidx[t][r] = 0; }

  STAGE_B(0, 0);
  __syncthreads();   // drains vmcnt(0) + barrier: buf0 ready

  int cur = 0;
  for (int bt = 0; bt < 16; ++bt) {
    if (bt < 15) STAGE_B(cur ^ 1, bt + 1);   // async prefetch overlaps MFMAs
    const int cidx = (bt << 4) + lr;
    const float c2v = c2[cidx];
    float4v acc[2];
#pragma unroll
    for (int t = 0; t < 2; ++t) acc[t] = (float4v){0.f, 0.f, 0.f, 0.f};
#pragma unroll
    for (int s = 0; s < 4; ++s) {
      const int ch = (((s << 2) + g) ^ (lr & 7)) << 3;
      const short8 bh = *(const short8*)&ldsb[cur][0][lr][ch];
      const short8 bl = *(const short8*)&ldsb[cur][1][lr][ch];
#pragma unroll
      for (int t = 0; t < 2; ++t) {
        acc[t] = __builtin_amdgcn_mfma_f32_16x16x32_bf16(ahi[t][s], bh, acc[t], 0, 0, 0);
        acc[t] = __builtin_amdgcn_mfma_f32_16x16x32_bf16(alo[t][s], bh, acc[t], 0, 0, 0);
        acc[t] = __builtin_amdgcn_mfma_f32_16x16x32_bf16(ahi[t][s], bl, acc[t], 0, 0, 0);
      }
    }
#pragma unroll
    for (int t = 0; t < 2; ++t)
#pragma unroll
      for (int r = 0; r < 4; ++r) {
        const float sc = fmaf(-2.0f, acc[t][r], c2v);
        if (sc < bestv[t][r]) { bestv[t][r] = sc; bidx[t][r] = cidx; }
      }
    __syncthreads();   // vmcnt(0) drain publishes next tile; read-done fence
    cur ^= 1;
  }

#pragma unroll
  for (int t = 0; t < 2; ++t)
#pragma unroll
    for (int r = 0; r < 4; ++r) {
      float v = bestv[t][r];
      int i = bidx[t][r];
#pragma unroll
      for (int m = 1; m < 16; m <<= 1) {
        const float ov = __shfl_xor(v, m);
        const int oi = __shfl_xor(i, m);
        if (ov < v || (ov == v && oi < i)) { v = ov; i = oi; }
      }
      if (lr == 0) assign[rowbase + t * 16 + g * 4 + r] = (unsigned char)i;
    }
#undef STAGE_B
}

// ---- means partials: 8 slices per cluster, grid K*8, atomic combine -----
// 8 blocks/CU (32 waves/CU); gather 8 rows in flight per wave for MLP.
#define SEG 4096
#define SLICES 8
__global__ __launch_bounds__(256) void k_means_part(const float* __restrict__ feat,
                                                    const unsigned char* __restrict__ assign,
                                                    float* __restrict__ sums,
                                                    float* __restrict__ counts, int N) {
  const int k = blockIdx.x >> 3;
  const int slice = blockIdx.x & (SLICES - 1);
  const int tid = threadIdx.x;
  const int wave = tid >> 6, lane = tid & 63;
  __shared__ float accsh[4][D];
  __shared__ int queue[SEG];
  __shared__ int qn, total;
  float ax = 0.0f, ay = 0.0f;   // lane's partial for dims 2*lane, 2*lane+1
  if (tid == 0) total = 0;
  const int sbeg = slice * (N / SLICES);
  const int send = sbeg + N / SLICES;
  for (int base = sbeg; base < send; base += SEG) {
    if (tid == 0) qn = 0;
    __syncthreads();
    const uint4 w = *(const uint4*)(assign + base + tid * 16);
    const uint words[4] = {w.x, w.y, w.z, w.w};
#pragma unroll
    for (int wq = 0; wq < 4; ++wq)
#pragma unroll
      for (int b = 0; b < 4; ++b) {
        if (((words[wq] >> (8 * b)) & 0xFFu) == (uint)k) {
          const int pos = atomicAdd(&qn, 1);
          queue[pos] = base + tid * 16 + wq * 4 + b;
        }
      }
    __syncthreads();
    const int n = qn;
    if (tid == 0) total += n;
    int r = wave;
    // 8 rows in flight per wave
    for (; r + 28 < n; r += 32) {
      int idx[8];
#pragma unroll
      for (int q = 0; q < 8; ++q) idx[q] = queue[r + 4 * q];
      float2 v[8];
#pragma unroll
      for (int q = 0; q < 8; ++q) v[q] = *(const float2*)(feat + (size_t)idx[q] * D + 2 * lane);
#pragma unroll
      for (int q = 0; q < 8; ++q) { ax += v[q].x; ay += v[q].y; }
    }
    // 4 rows in flight
    for (; r + 12 < n; r += 16) {
      const int i0 = queue[r], i1 = queue[r + 4], i2 = queue[r + 8], i3 = queue[r + 12];
      const float2 v0 = *(const float2*)(feat + (size_t)i0 * D + 2 * lane);
      const float2 v1 = *(const float2*)(feat + (size_t)i1 * D + 2 * lane);
      const float2 v2 = *(const float2*)(feat + (size_t)i2 * D + 2 * lane);
      const float2 v3 = *(const float2*)(feat + (size_t)i3 * D + 2 * lane);
      ax += (v0.x + v1.x) + (v2.x + v3.x);
      ay += (v0.y + v1.y) + (v2.y + v3.y);
    }
    for (; r < n; r += 4) {
      const float2 v = *(const float2*)(feat + (size_t)queue[r] * D + 2 * lane);
      ax += v.x;
      ay += v.y;
    }
    __syncthreads();
  }
  accsh[wave][2 * lane] = ax;
  accsh[wave][2 * lane + 1] = ay;
  __syncthreads();
  if (tid < D) {
    const float s = (accsh[0][tid] + accsh[1][tid]) + (accsh[2][tid] + accsh[3][tid]);
    atomicAdd(&sums[k * D + tid], s);
  }
  if (tid == 0 && total > 0) atomicAdd(&counts[k], (float)total);
}

// ---- finalize means: sums/count in place --------------------------------
__global__ __launch_bounds__(128) void k_meansfin(float* __restrict__ sums,
                                                  const float* __restrict__ counts) {
  const int k = blockIdx.x, d = threadIdx.x;
  sums[k * D + d] /= fmaxf(counts[k], 1.0f);
}

// ---- deviations: wave-per-row coalesced, shfl reduce, 4 rows/iter -------
// stride 16, rows {r, r+4, r+8, r+12}: residues (mod 16) = {w,w+4,w+8,w+12}
// for w=0..3 cover 0..15 exactly once.
__global__ __launch_bounds__(256) void k_dev(const float* __restrict__ feat,
                                             const unsigned char* __restrict__ assign,
                                             const float* __restrict__ means,
                                             float* __restrict__ devsum) {
  __shared__ float dacc[K];
  const int tid = threadIdx.x;
  const int wave = tid >> 6, lane = tid & 63;
  dacc[tid] = 0.0f;
  __syncthreads();
  const int rowbase = blockIdx.x * 256;
  for (int r = wave; r < 256; r += 16) {   // 4 rows (8 loads) in flight
    const int r0 = rowbase + r, r1 = rowbase + r + 4;
    const int r2 = rowbase + r + 8, r3 = rowbase + r + 12;
    const int a0 = (int)assign[r0];
    const int a1 = (int)assign[r1];
    const int a2 = (int)assign[r2];
    const int a3 = (int)assign[r3];
    const float2 f0 = *(const float2*)(feat + (size_t)r0 * D + 2 * lane);
    const float2 m0 = *(const float2*)(means + (size_t)a0 * D + 2 * lane);
    const float2 f1 = *(const float2*)(feat + (size_t)r1 * D + 2 * lane);
    const float2 m1 = *(const float2*)(means + (size_t)a1 * D + 2 * lane);
    const float2 f2 = *(const float2*)(feat + (size_t)r2 * D + 2 * lane);
    const float2 m2 = *(const float2*)(means + (size_t)a2 * D + 2 * lane);
    const float2 f3 = *(const float2*)(feat + (size_t)r3 * D + 2 * lane);
    const float2 m3 = *(const float2*)(means + (size_t)a3 * D + 2 * lane);
    const float dx0 = f0.x - m0.x, dy0 = f0.y - m0.y;
    const float dx1 = f1.x - m1.x, dy1 = f1.y - m1.y;
    const float dx2 = f2.x - m2.x, dy2 = f2.y - m2.y;
    const float dx3 = f3.x - m3.x, dy3 = f3.y - m3.y;
    float s0 = fmaf(dx0, dx0, dy0 * dy0);
    float s1 = fmaf(dx1, dx1, dy1 * dy1);
    float s2 = fmaf(dx2, dx2, dy2 * dy2);
    float s3 = fmaf(dx3, dx3, dy3 * dy3);
#pragma unroll
    for (int m = 1; m < 64; m <<= 1) {
      s0 += __shfl_xor(s0, m);
      s1 += __shfl_xor(s1, m);
      s2 += __shfl_xor(s2, m);
      s3 += __shfl_xor(s3, m);
    }
    if (lane == 0) {
      atomicAdd(&dacc[a0], sqrtf(s0));
      atomicAdd(&dacc[a1], sqrtf(s1));
      atomicAdd(&dacc[a2], sqrtf(s2));
      atomicAdd(&dacc[a3], sqrtf(s3));
    }
  }
  __syncthreads();
  atomicAdd(&devsum[tid], dacc[tid]);
}

// ---- final scalar combine -----------------------------------------------
__global__ __launch_bounds__(256) void k_final(const float* __restrict__ ws,
                                               float* __restrict__ out) {
  __shared__ float s_pc[K];
  __shared__ float s_v[K];
  const int t = threadIdx.x;
  const float c = ws[WS_COUNTS + t];
  const float pc = ws[WS_DEVSUM + t] / fmaxf(c, 1.0f);
  const float valid = (c > 1.0f) ? 1.0f : 0.0f;
  s_pc[t] = valid * pc;
  s_v[t] = valid;
  __syncthreads();
  for (int s = 128; s > 0; s >>= 1) {
    if (t < s) { s_pc[t] += s_pc[t + s]; s_v[t] += s_v[t + s]; }
    __syncthreads();
  }
  if (t == 0) {
    const float nv = s_v[0];
    const float intra = (nv > 0.0f) ? (s_pc[0] / fmaxf(nv, 1.0f)) : 0.0f;
    // triu(.,1) zeroed K + K(K-1)/2 = 32896 entries; zeros < margin => counted
    const float inter = (ws[WS_INTER] + 32896.0f) / 32640.0f;
    out[0] = intra + inter;
  }
}

extern "C" void kernel_launch(void* const* d_in, const int* in_sizes, int n_in,
                              void* d_out, int out_size, void* d_ws, size_t ws_size,
                              hipStream_t stream) {
  const float* feat = (const float*)d_in[0];
  const float* centers = (const float*)d_in[1];
  float* out = (float*)d_out;
  float* ws = (float*)d_ws;
  const int N = in_sizes[0] / D;
  const ushort* chi = (const ushort*)(ws + WS_CHI);
  const ushort* clo = (const ushort*)(ws + WS_CLO);
  unsigned char* assign = (unsigned char*)(ws + WS_ASSIGN);

  k_cprep<<<K, D, 0, stream>>>(centers, ws);
  k_inter<<<K, 256, 0, stream>>>(centers, ws);
  k_assign<<<N / 128, 256, 0, stream>>>(feat, chi, clo, ws + WS_C2, assign);
  k_means_part<<<K * SLICES, 256, 0, stream>>>(feat, assign, ws + WS_MEANS, ws + WS_COUNTS, N);
  k_meansfin<<<K, D, 0, stream>>>(ws + WS_MEANS, ws + WS_COUNTS);
  k_dev<<<N / 256, 256, 0, stream>>>(feat, assign, ws + WS_MEANS, ws + WS_DEVSUM);
  k_final<<<1, 256, 0, stream>>>(ws, out);
}